// Round 3
// baseline (3157.824 us; speedup 1.0000x reference)
//
#include <hip/hip_runtime.h>
#include <math.h>

#define NB 16
#define NC 32
#define NR 256
#define NE 256
#define NH 4
#define HDIM 64
#define F3 768

// ws layout (floats):  ctx [B][C][R][256]  then  part [B*C][8][256]
#define CTX_ELEMS  (16ULL*32*256*256)   // 33,554,432
#define PART_ELEMS (512ULL*8*256)       //  1,048,576
#define WS_REQUIRED ((CTX_ELEMS + PART_ELEMS) * 4ULL)   // ~138 MB

// ---------------------------------------------------------------------------
// K1: fused QKV projection + flash attention, one block per (b,c,h).
//  - thread t owns q-row t (64 regs), q = (x@wq^T + bq) * 1/8
//  - per 64-row s-tile: K,V tile GEMM -> LDS, then online-softmax attn step
// ---------------------------------------------------------------------------
__global__ __launch_bounds__(256) void k_fused_attn(
    const float* __restrict__ x, const float* __restrict__ wqkv,
    const float* __restrict__ bqkv, const int* __restrict__ cols,
    const int* __restrict__ rows, float* __restrict__ ctx)
{
    int blk = blockIdx.x;              // (b*32+c)*4 + h
    int h = blk & 3, bc = blk >> 2;
    int b = bc >> 5, c = bc & 31;
    if (c >= cols[b]) return;
    int rv = rows[b];
    int t = threadIdx.x;
    int nst = (rv + 63) >> 6;

    __shared__ float Kt[64][64];       // 16 KB, attn reads are lane-uniform (broadcast)
    __shared__ float Vt[64][64];       // 16 KB
    __shared__ float Xs[64][33];       // staging: x tile / wq chunk (+1 pad)
    __shared__ float Bs[32][68];       // staging: w tile, transposed (+4 pad, f4-aligned)

    const float* xbc = x + (size_t)bc * (NR * NE);

    // ---- q phase: q[d] = (sum_e x[t,e]*wq[h*64+d,e] + bq) * 0.125
    float q[HDIM];
    #pragma unroll
    for (int d = 0; d < HDIM; ++d) q[d] = 0.f;
    for (int e0 = 0; e0 < NE; e0 += 32) {
        #pragma unroll
        for (int m = 0; m < 8; ++m) {
            int idx = t + (m << 8);
            int d = idx >> 5, e = idx & 31;
            Xs[d][e] = wqkv[(size_t)(h * HDIM + d) * NE + e0 + e];
        }
        __syncthreads();
        if (t < rv) {
            float xr[32];
            const float* xp = xbc + (size_t)t * NE + e0;
            #pragma unroll
            for (int e = 0; e < 32; e += 4) {
                float4 v = *(const float4*)(xp + e);
                xr[e] = v.x; xr[e+1] = v.y; xr[e+2] = v.z; xr[e+3] = v.w;
            }
            #pragma unroll
            for (int d = 0; d < HDIM; ++d) {
                float s = q[d];
                #pragma unroll
                for (int e = 0; e < 32; e += 4) {
                    float4 wv = *(const float4*)&Xs[d][e];
                    s = fmaf(xr[e],   wv.x, s); s = fmaf(xr[e+1], wv.y, s);
                    s = fmaf(xr[e+2], wv.z, s); s = fmaf(xr[e+3], wv.w, s);
                }
                q[d] = s;
            }
        }
        __syncthreads();
    }
    if (t < rv) {
        #pragma unroll
        for (int d = 0; d < HDIM; ++d)
            q[d] = (q[d] + bqkv[h * HDIM + d]) * 0.125f;
    }

    float mrun = -INFINITY, l = 0.f;
    float cacc[HDIM];
    #pragma unroll
    for (int d = 0; d < HDIM; ++d) cacc[d] = 0.f;

    for (int st = 0; st < nst; ++st) {
        int s0 = st << 6;
        int ns = min(64, rv - s0);     // wave-uniform

        // ---- K (dt=0) then V (dt=1) 64x64 tile GEMM into LDS
        #pragma unroll
        for (int dt = 0; dt < 2; ++dt) {
            int fb = 256 + dt * 256 + h * HDIM;
            float acc[4][4];
            #pragma unroll
            for (int i = 0; i < 4; ++i)
                #pragma unroll
                for (int j = 0; j < 4; ++j) acc[i][j] = 0.f;
            for (int e0 = 0; e0 < NE; e0 += 32) {
                #pragma unroll
                for (int m = 0; m < 8; ++m) {
                    int idx = t + (m << 8);
                    int i = idx >> 5, kk = idx & 31;
                    Xs[i][kk] = xbc[(size_t)(s0 + i) * NE + e0 + kk];  // s0+i<=255: valid mem
                }
                #pragma unroll
                for (int m = 0; m < 8; ++m) {
                    int idx = t + (m << 8);
                    int j = idx >> 5, kk = idx & 31;
                    Bs[kk][j] = wqkv[(size_t)(fb + j) * NE + e0 + kk];
                }
                __syncthreads();
                int i0 = (t >> 4) * 4, j0 = (t & 15) * 4;
                #pragma unroll
                for (int kk = 0; kk < 32; ++kk) {
                    float a0 = Xs[i0+0][kk], a1 = Xs[i0+1][kk];
                    float a2 = Xs[i0+2][kk], a3 = Xs[i0+3][kk];
                    float4 bv = *(const float4*)&Bs[kk][j0];
                    acc[0][0]=fmaf(a0,bv.x,acc[0][0]); acc[0][1]=fmaf(a0,bv.y,acc[0][1]);
                    acc[0][2]=fmaf(a0,bv.z,acc[0][2]); acc[0][3]=fmaf(a0,bv.w,acc[0][3]);
                    acc[1][0]=fmaf(a1,bv.x,acc[1][0]); acc[1][1]=fmaf(a1,bv.y,acc[1][1]);
                    acc[1][2]=fmaf(a1,bv.z,acc[1][2]); acc[1][3]=fmaf(a1,bv.w,acc[1][3]);
                    acc[2][0]=fmaf(a2,bv.x,acc[2][0]); acc[2][1]=fmaf(a2,bv.y,acc[2][1]);
                    acc[2][2]=fmaf(a2,bv.z,acc[2][2]); acc[2][3]=fmaf(a2,bv.w,acc[2][3]);
                    acc[3][0]=fmaf(a3,bv.x,acc[3][0]); acc[3][1]=fmaf(a3,bv.y,acc[3][1]);
                    acc[3][2]=fmaf(a3,bv.z,acc[3][2]); acc[3][3]=fmaf(a3,bv.w,acc[3][3]);
                }
                __syncthreads();
            }
            int i0 = (t >> 4) * 4, j0 = (t & 15) * 4;
            float* dst = dt ? &Vt[0][0] : &Kt[0][0];
            #pragma unroll
            for (int ii = 0; ii < 4; ++ii)
                #pragma unroll
                for (int jj = 0; jj < 4; ++jj)
                    dst[(i0 + ii) * 64 + j0 + jj] = acc[ii][jj] + bqkv[fb + j0 + jj];
        }
        __syncthreads();               // Kt/Vt ready

        // ---- online-softmax attention step over this 64-row tile
        if (t < rv) {
            for (int ss = 0; ss < ns; ss += 16) {
                float sc[16];
                float tmax = -INFINITY;
                #pragma unroll
                for (int u = 0; u < 16; ++u) {
                    float dot = 0.f;
                    #pragma unroll
                    for (int d = 0; d < HDIM; d += 4) {
                        float4 kv = *(const float4*)&Kt[ss + u][d];
                        dot = fmaf(q[d],   kv.x, dot); dot = fmaf(q[d+1], kv.y, dot);
                        dot = fmaf(q[d+2], kv.z, dot); dot = fmaf(q[d+3], kv.w, dot);
                    }
                    sc[u] = (ss + u < ns) ? dot : -INFINITY;
                    tmax = fmaxf(tmax, sc[u]);
                }
                float mnew = fmaxf(mrun, tmax);
                float r = __expf(mrun - mnew);      // first tile: exp(-inf)=0
                l *= r;
                #pragma unroll
                for (int d = 0; d < HDIM; ++d) cacc[d] *= r;
                #pragma unroll
                for (int u = 0; u < 16; ++u) {
                    float p = __expf(sc[u] - mnew); // masked: exp(-inf)=0
                    l += p;
                    #pragma unroll
                    for (int d = 0; d < HDIM; d += 4) {
                        float4 vv = *(const float4*)&Vt[ss + u][d];
                        cacc[d+0] = fmaf(p, vv.x, cacc[d+0]);
                        cacc[d+1] = fmaf(p, vv.y, cacc[d+1]);
                        cacc[d+2] = fmaf(p, vv.z, cacc[d+2]);
                        cacc[d+3] = fmaf(p, vv.w, cacc[d+3]);
                    }
                }
                mrun = mnew;
            }
        }
        __syncthreads();               // before next tile overwrites Kt/Vt
    }

    if (t < rv) {
        float inv = 1.f / l;
        float* op = ctx + ((size_t)bc * NR + t) * NE + h * HDIM;
        #pragma unroll
        for (int d = 0; d < HDIM; d += 4) {
            float4 o;
            o.x = cacc[d]*inv; o.y = cacc[d+1]*inv;
            o.z = cacc[d+2]*inv; o.w = cacc[d+3]*inv;
            *(float4*)(op + d) = o;
        }
    }
}

// ---------------------------------------------------------------------------
// K2: fused out-proj + LayerNorm + FFN + residual + per-tile row-sum.
// One block per (b,c, 32-row tile). Thread tx owns output feature f=tx.
// ---------------------------------------------------------------------------
__global__ __launch_bounds__(256) void k_ffn(
    const float* __restrict__ ctx,
    const float* __restrict__ wout, const float* __restrict__ bout,
    const float* __restrict__ lng, const float* __restrict__ lnb,
    const float* __restrict__ w1, const float* __restrict__ b1,
    const float* __restrict__ w2, const float* __restrict__ b2,
    const int* __restrict__ cols, const int* __restrict__ rows,
    float* __restrict__ part)
{
    int bc = blockIdx.x;
    int b = bc >> 5, c = bc & 31;
    if (c >= cols[b]) return;
    int rv = rows[b];
    int row0 = blockIdx.y * 32;
    if (row0 >= rv) return;
    int nr = min(32, rv - row0);
    int tx = threadIdx.x;

    __shared__ float A[32][260];     // stride 260: f4-aligned rows, spreads banks
    __shared__ float Bb[32][260];
    __shared__ float smu[32], srs[32];

    const float* cp = ctx + ((size_t)bc * NR + row0) * NE;
    #pragma unroll
    for (int mm = 0; mm < 32; ++mm)
        A[mm][tx] = cp[(size_t)mm * NE + tx];   // rows>=nr: stale ws, finite, masked later
    __syncthreads();

    float acc[32];

    // ---- GEMM1: attn_out[:,tx] = A @ wout[tx,:]^T + bout[tx]
    #pragma unroll
    for (int i = 0; i < 32; ++i) acc[i] = 0.f;
    {
        const float* wr = wout + (size_t)tx * NE;
        for (int e = 0; e < NE; e += 4) {
            float4 wv = *(const float4*)(wr + e);
            #pragma unroll
            for (int i = 0; i < 32; ++i) {
                float4 av = *(const float4*)&A[i][e];   // broadcast
                acc[i]=fmaf(av.x,wv.x,acc[i]); acc[i]=fmaf(av.y,wv.y,acc[i]);
                acc[i]=fmaf(av.z,wv.z,acc[i]); acc[i]=fmaf(av.w,wv.w,acc[i]);
            }
        }
    }
    float bo = bout[tx];
    #pragma unroll
    for (int i = 0; i < 32; ++i) Bb[i][tx] = acc[i] + bo;
    __syncthreads();

    // ---- LN stats: 8 lanes/row strided + shfl reduce
    {
        int rowi = tx >> 3, g = tx & 7;
        float s = 0.f, ss = 0.f;
        #pragma unroll
        for (int mm = 0; mm < 32; ++mm) {
            float v = Bb[rowi][g + (mm << 3)];
            s += v; ss = fmaf(v, v, ss);
        }
        s += __shfl_xor(s, 1); ss += __shfl_xor(ss, 1);
        s += __shfl_xor(s, 2); ss += __shfl_xor(ss, 2);
        s += __shfl_xor(s, 4); ss += __shfl_xor(ss, 4);
        if (g == 0) {
            float mu = s * (1.f / 256.f);
            float var = ss * (1.f / 256.f) - mu * mu;   // biased var, matches jnp
            smu[rowi] = mu;
            srs[rowi] = rsqrtf(var + 1e-5f);
        }
    }
    __syncthreads();

    // ---- LN apply -> A
    {
        float ge = lng[tx], be = lnb[tx];
        #pragma unroll
        for (int i = 0; i < 32; ++i)
            A[i][tx] = fmaf((Bb[i][tx] - smu[i]) * srs[i], ge, be);
    }
    __syncthreads();

    // ---- GEMM2: h = relu(ln @ w1^T + b1) -> Bb
    #pragma unroll
    for (int i = 0; i < 32; ++i) acc[i] = 0.f;
    {
        const float* wr = w1 + (size_t)tx * NE;
        for (int e = 0; e < NE; e += 4) {
            float4 wv = *(const float4*)(wr + e);
            #pragma unroll
            for (int i = 0; i < 32; ++i) {
                float4 av = *(const float4*)&A[i][e];
                acc[i]=fmaf(av.x,wv.x,acc[i]); acc[i]=fmaf(av.y,wv.y,acc[i]);
                acc[i]=fmaf(av.z,wv.z,acc[i]); acc[i]=fmaf(av.w,wv.w,acc[i]);
            }
        }
    }
    float b1v = b1[tx];
    #pragma unroll
    for (int i = 0; i < 32; ++i) Bb[i][tx] = fmaxf(acc[i] + b1v, 0.f);
    __syncthreads();

    // ---- GEMM3 + residual + column sum over valid rows
    #pragma unroll
    for (int i = 0; i < 32; ++i) acc[i] = 0.f;
    {
        const float* wr = w2 + (size_t)tx * NE;
        for (int e = 0; e < NE; e += 4) {
            float4 wv = *(const float4*)(wr + e);
            #pragma unroll
            for (int i = 0; i < 32; ++i) {
                float4 av = *(const float4*)&Bb[i][e];
                acc[i]=fmaf(av.x,wv.x,acc[i]); acc[i]=fmaf(av.y,wv.y,acc[i]);
                acc[i]=fmaf(av.z,wv.z,acc[i]); acc[i]=fmaf(av.w,wv.w,acc[i]);
            }
        }
    }
    float b2v = b2[tx];
    float colsum = 0.f;
    #pragma unroll
    for (int i = 0; i < 32; ++i)
        colsum += (i < nr) ? (acc[i] + b2v + A[i][tx]) : 0.f;
    part[((size_t)bc * 8 + blockIdx.y) * NE + tx] = colsum;
}

// ---------------------------------------------------------------------------
// K3: finalize rep[b,c,:] = valid ? sum(part)/rv : 0
// ---------------------------------------------------------------------------
__global__ __launch_bounds__(256) void k_final(
    const float* __restrict__ part, const int* __restrict__ cols,
    const int* __restrict__ rows, float* __restrict__ out)
{
    int bc = blockIdx.x;
    int tx = threadIdx.x;
    int b = bc >> 5, c = bc & 31;
    float v = 0.f;
    if (c < cols[b]) {
        int rv = rows[b];
        int nt = (rv + 31) >> 5;
        float s = 0.f;
        for (int t2 = 0; t2 < nt; ++t2)
            s += part[((size_t)bc * 8 + t2) * NE + tx];
        v = s / (float)rv;
    }
    out[(size_t)bc * NE + tx] = v;
}

extern "C" void kernel_launch(void* const* d_in, const int* in_sizes, int n_in,
                              void* d_out, int out_size, void* d_ws, size_t ws_size,
                              hipStream_t stream)
{
    const float* x    = (const float*)d_in[0];
    const int*   cols = (const int*)d_in[1];
    const int*   rows = (const int*)d_in[2];
    const float* wqkv = (const float*)d_in[3];
    const float* bqkv = (const float*)d_in[4];
    const float* wout = (const float*)d_in[5];
    const float* bout = (const float*)d_in[6];
    const float* lng  = (const float*)d_in[7];
    const float* lnb  = (const float*)d_in[8];
    const float* w1   = (const float*)d_in[9];
    const float* b1   = (const float*)d_in[10];
    const float* w2   = (const float*)d_in[11];
    const float* b2   = (const float*)d_in[12];
    float* out = (float*)d_out;

    if (ws_size < WS_REQUIRED) return;   // graceful fail (poison absmax), not a fault

    float* ctx  = (float*)d_ws;
    float* part = ctx + CTX_ELEMS;

    k_fused_attn<<<dim3(NB * NC * NH), 256, 0, stream>>>(x, wqkv, bqkv, cols, rows, ctx);
    k_ffn  <<<dim3(NB * NC, NR / 32), 256, 0, stream>>>(ctx, wout, bout, lng, lnb,
                                                        w1, b1, w2, b2, cols, rows, part);
    k_final<<<dim3(NB * NC), 256, 0, stream>>>(part, cols, rows, out);
}

// Round 4
// 1135.104 us; speedup vs baseline: 2.7820x; 2.7820x over previous
//
#include <hip/hip_runtime.h>
#include <math.h>

#define NB 16
#define NC 32
#define NR 256
#define NE 256
#define NH 4
#define HDIM 64
#define F3 768

// ws layout:
//   qkv  bf16 [B][C][R][768]  (q cols 0..255 pre-scaled/biased; ctx overwrites q-slot)
//   part f32  [B*C][8][256]
#define QKV_ELEMS  (16ULL*32*256*768)            // 100,663,296 bf16
#define PART_OFF_F (QKV_ELEMS / 2)               // float offset of part
#define WS_REQUIRED (QKV_ELEMS*2ULL + 512ULL*8*256*4)   // 205,520,896 B

typedef __attribute__((ext_vector_type(8))) short   short8v;   // MFMA A/B frag (8 bf16)
typedef __attribute__((ext_vector_type(4))) float   f32x4;     // MFMA C/D frag
typedef __attribute__((ext_vector_type(8))) unsigned short u16x8;

static __device__ __forceinline__ unsigned short f2bf(float f) {   // RNE f32->bf16
    unsigned u = __builtin_bit_cast(unsigned, f);
    u += 0x7FFFu + ((u >> 16) & 1u);
    return (unsigned short)(u >> 16);
}
static __device__ __forceinline__ float bf2f(unsigned short s) {
    unsigned u = ((unsigned)s) << 16;
    return __builtin_bit_cast(float, u);
}

// ---------------------------------------------------------------------------
// K1: QKV projection, bf16 MFMA.  qkv[r][f] = (x[r]·wqkv[f] + b[f]) (*0.125 if f<256)
// 64x64 tile, BK=64, 4 waves (wave owns 16 m-rows, all 64 n-cols).
// A-frag: lane reads As[16w + (l&15)][kf*32 + (l>>4)*8]  (contiguous b128)
// B-frag: lane reads Bs[n*16 + (l&15)][kf*32 + (l>>4)*8]
// D: row = (l>>4)*4 + j, col = l&15   [m89/m91-verified layout]
// ---------------------------------------------------------------------------
__global__ __launch_bounds__(256) void k_qkvproj(
    const float* __restrict__ x, const float* __restrict__ wqkv,
    const float* __restrict__ bqkv, const int* __restrict__ cols,
    const int* __restrict__ rows, unsigned short* __restrict__ qkv)
{
    int bc = blockIdx.x;
    int b = bc >> 5, c = bc & 31;
    if (c >= cols[b]) return;
    int rv = rows[b];
    int row0 = blockIdx.y * 64;
    if (row0 >= rv) return;
    int f0 = blockIdx.z * 64;

    __shared__ short As[64][72];   // bf16, +8 pad: 144B row stride -> 2-way banks on frag reads
    __shared__ short Bs[64][72];

    int t = threadIdx.x;
    int wave = t >> 6, lane = t & 63;
    const float* xbc = x + (size_t)bc * (NR * NE);

    f32x4 acc[4];
    #pragma unroll
    for (int n = 0; n < 4; ++n) acc[n] = (f32x4){0.f, 0.f, 0.f, 0.f};

    for (int k0 = 0; k0 < NE; k0 += 64) {
        #pragma unroll
        for (int rr = 0; rr < 64; rr += 16) {
            int i = (t >> 4) + rr, kk = (t & 15) * 4;
            float4 v = *(const float4*)(xbc + (size_t)(row0 + i) * NE + k0 + kk);
            *(short4*)&As[i][kk] = make_short4((short)f2bf(v.x), (short)f2bf(v.y),
                                               (short)f2bf(v.z), (short)f2bf(v.w));
            float4 w = *(const float4*)(wqkv + (size_t)(f0 + i) * NE + k0 + kk);
            *(short4*)&Bs[i][kk] = make_short4((short)f2bf(w.x), (short)f2bf(w.y),
                                               (short)f2bf(w.z), (short)f2bf(w.w));
        }
        __syncthreads();
        #pragma unroll
        for (int kf = 0; kf < 2; ++kf) {
            short8v av = *(const short8v*)&As[16 * wave + (lane & 15)][kf * 32 + (lane >> 4) * 8];
            #pragma unroll
            for (int n = 0; n < 4; ++n) {
                short8v bv = *(const short8v*)&Bs[n * 16 + (lane & 15)][kf * 32 + (lane >> 4) * 8];
                acc[n] = __builtin_amdgcn_mfma_f32_16x16x32_bf16(av, bv, acc[n], 0, 0, 0);
            }
        }
        __syncthreads();
    }

    int rbase = row0 + 16 * wave + ((lane >> 4) << 2);
    #pragma unroll
    for (int n = 0; n < 4; ++n) {
        int f = f0 + n * 16 + (lane & 15);
        float bias = bqkv[f];
        float scl = (f < 256) ? 0.125f : 1.f;
        #pragma unroll
        for (int jj = 0; jj < 4; ++jj) {
            float val = (acc[n][jj] + bias) * scl;
            qkv[(size_t)((size_t)bc * NR + rbase + jj) * F3 + f] = f2bf(val);
        }
    }
}

// ---------------------------------------------------------------------------
// K2: flash attention per (b,c,h) from precomputed bf16 qkv.
// Thread t owns q-row t; K/V tiles staged bf16->f32 LDS (2 barriers/tile).
// ctx written back into the q-slot (cols h*64..h*64+63), bf16.
// ---------------------------------------------------------------------------
__global__ __launch_bounds__(256) void k_attn(
    unsigned short* __restrict__ qkv, const int* __restrict__ cols,
    const int* __restrict__ rows)
{
    int blk = blockIdx.x;              // (b*32+c)*4 + h
    int h = blk & 3, bc = blk >> 2;
    int b = bc >> 5, c = bc & 31;
    if (c >= cols[b]) return;
    int rv = rows[b];
    int t = threadIdx.x;
    int nst = (rv + 63) >> 6;

    __shared__ float Kt[64][64];       // broadcast-read in attn core: conflict-free
    __shared__ float Vt[64][64];

    unsigned short* base = qkv + (size_t)bc * NR * F3;

    float q[HDIM];
    if (t < rv) {
        #pragma unroll
        for (int c8 = 0; c8 < 8; ++c8) {
            u16x8 uv = *(const u16x8*)(base + (size_t)t * F3 + h * HDIM + c8 * 8);
            #pragma unroll
            for (int j = 0; j < 8; ++j) q[c8 * 8 + j] = bf2f(uv[j]);
        }
    }

    float mrun = -INFINITY, l = 0.f;
    float cacc[HDIM];
    #pragma unroll
    for (int d = 0; d < HDIM; ++d) cacc[d] = 0.f;

    for (int st = 0; st < nst; ++st) {
        int s0 = st << 6;
        int ns = min(64, rv - s0);     // wave-uniform

        // stage K,V tiles: 64 rows x 8 chunks of 8 bf16; 2 slots/thread each
        #pragma unroll
        for (int rep = 0; rep < 2; ++rep) {
            int slot = t + rep * 256;
            int s = slot >> 3, ch = slot & 7;
            const unsigned short* rp = base + (size_t)(s0 + s) * F3 + h * HDIM + ch * 8;
            u16x8 kv = *(const u16x8*)(rp + 256);
            u16x8 vv = *(const u16x8*)(rp + 512);
            float4 k0 = {bf2f(kv[0]), bf2f(kv[1]), bf2f(kv[2]), bf2f(kv[3])};
            float4 k1 = {bf2f(kv[4]), bf2f(kv[5]), bf2f(kv[6]), bf2f(kv[7])};
            float4 v0 = {bf2f(vv[0]), bf2f(vv[1]), bf2f(vv[2]), bf2f(vv[3])};
            float4 v1 = {bf2f(vv[4]), bf2f(vv[5]), bf2f(vv[6]), bf2f(vv[7])};
            *(float4*)&Kt[s][ch * 8]     = k0;
            *(float4*)&Kt[s][ch * 8 + 4] = k1;
            *(float4*)&Vt[s][ch * 8]     = v0;
            *(float4*)&Vt[s][ch * 8 + 4] = v1;
        }
        __syncthreads();

        if (t < rv) {
            for (int ss = 0; ss < ns; ss += 16) {
                float sc[16];
                float tmax = -INFINITY;
                #pragma unroll
                for (int u = 0; u < 16; ++u) {
                    float dot = 0.f;
                    #pragma unroll
                    for (int d = 0; d < HDIM; d += 4) {
                        float4 kv = *(const float4*)&Kt[ss + u][d];
                        dot = fmaf(q[d],   kv.x, dot); dot = fmaf(q[d+1], kv.y, dot);
                        dot = fmaf(q[d+2], kv.z, dot); dot = fmaf(q[d+3], kv.w, dot);
                    }
                    sc[u] = (ss + u < ns) ? dot : -INFINITY;
                    tmax = fmaxf(tmax, sc[u]);
                }
                float mnew = fmaxf(mrun, tmax);
                float r = __expf(mrun - mnew);      // first tile: exp(-inf)=0
                l *= r;
                #pragma unroll
                for (int d = 0; d < HDIM; ++d) cacc[d] *= r;
                #pragma unroll
                for (int u = 0; u < 16; ++u) {
                    float p = __expf(sc[u] - mnew); // masked: exp(-inf)=0
                    l += p;
                    #pragma unroll
                    for (int d = 0; d < HDIM; d += 4) {
                        float4 vv = *(const float4*)&Vt[ss + u][d];
                        cacc[d+0] = fmaf(p, vv.x, cacc[d+0]);
                        cacc[d+1] = fmaf(p, vv.y, cacc[d+1]);
                        cacc[d+2] = fmaf(p, vv.z, cacc[d+2]);
                        cacc[d+3] = fmaf(p, vv.w, cacc[d+3]);
                    }
                }
                mrun = mnew;
            }
        }
        __syncthreads();               // before next tile overwrites Kt/Vt
    }

    // write ctx into the q-slot (all q reads happened before the loop; barriers passed)
    if (t < rv) {
        float inv = 1.f / l;
        #pragma unroll
        for (int c8 = 0; c8 < 8; ++c8) {
            u16x8 o;
            #pragma unroll
            for (int j = 0; j < 8; ++j) o[j] = f2bf(cacc[c8 * 8 + j] * inv);
            *(u16x8*)(base + (size_t)t * F3 + h * HDIM + c8 * 8) = o;
        }
    }
}

// ---------------------------------------------------------------------------
// K3: fused out-proj + LayerNorm + FFN + residual + per-tile row-sum (fp32).
// ctx read as bf16 from the qkv q-slot (row stride 768).
// ---------------------------------------------------------------------------
__global__ __launch_bounds__(256) void k_ffn(
    const unsigned short* __restrict__ qkv,
    const float* __restrict__ wout, const float* __restrict__ bout,
    const float* __restrict__ lng, const float* __restrict__ lnb,
    const float* __restrict__ w1, const float* __restrict__ b1,
    const float* __restrict__ w2, const float* __restrict__ b2,
    const int* __restrict__ cols, const int* __restrict__ rows,
    float* __restrict__ part)
{
    int bc = blockIdx.x;
    int b = bc >> 5, c = bc & 31;
    if (c >= cols[b]) return;
    int rv = rows[b];
    int row0 = blockIdx.y * 32;
    if (row0 >= rv) return;
    int nr = min(32, rv - row0);
    int tx = threadIdx.x;

    __shared__ float A[32][260];     // stride 260: f4-aligned rows, spreads banks
    __shared__ float Bb[32][260];
    __shared__ float smu[32], srs[32];

    const unsigned short* cp = qkv + (size_t)((size_t)bc * NR + row0) * F3;
    #pragma unroll
    for (int mm = 0; mm < 32; ++mm)
        A[mm][tx] = bf2f(cp[(size_t)mm * F3 + tx]);  // rows>=nr: finite K1 q vals, masked later
    __syncthreads();

    float acc[32];

    // ---- GEMM1: attn_out[:,tx] = A @ wout[tx,:]^T + bout[tx]
    #pragma unroll
    for (int i = 0; i < 32; ++i) acc[i] = 0.f;
    {
        const float* wr = wout + (size_t)tx * NE;
        for (int e = 0; e < NE; e += 4) {
            float4 wv = *(const float4*)(wr + e);
            #pragma unroll
            for (int i = 0; i < 32; ++i) {
                float4 av = *(const float4*)&A[i][e];   // broadcast
                acc[i]=fmaf(av.x,wv.x,acc[i]); acc[i]=fmaf(av.y,wv.y,acc[i]);
                acc[i]=fmaf(av.z,wv.z,acc[i]); acc[i]=fmaf(av.w,wv.w,acc[i]);
            }
        }
    }
    float bo = bout[tx];
    #pragma unroll
    for (int i = 0; i < 32; ++i) Bb[i][tx] = acc[i] + bo;
    __syncthreads();

    // ---- LN stats: 8 lanes/row strided + shfl reduce
    {
        int rowi = tx >> 3, g = tx & 7;
        float s = 0.f, ss = 0.f;
        #pragma unroll
        for (int mm = 0; mm < 32; ++mm) {
            float v = Bb[rowi][g + (mm << 3)];
            s += v; ss = fmaf(v, v, ss);
        }
        s += __shfl_xor(s, 1); ss += __shfl_xor(ss, 1);
        s += __shfl_xor(s, 2); ss += __shfl_xor(ss, 2);
        s += __shfl_xor(s, 4); ss += __shfl_xor(ss, 4);
        if (g == 0) {
            float mu = s * (1.f / 256.f);
            float var = ss * (1.f / 256.f) - mu * mu;   // biased var, matches jnp
            smu[rowi] = mu;
            srs[rowi] = rsqrtf(var + 1e-5f);
        }
    }
    __syncthreads();

    // ---- LN apply -> A
    {
        float ge = lng[tx], be = lnb[tx];
        #pragma unroll
        for (int i = 0; i < 32; ++i)
            A[i][tx] = fmaf((Bb[i][tx] - smu[i]) * srs[i], ge, be);
    }
    __syncthreads();

    // ---- GEMM2: h = relu(ln @ w1^T + b1) -> Bb
    #pragma unroll
    for (int i = 0; i < 32; ++i) acc[i] = 0.f;
    {
        const float* wr = w1 + (size_t)tx * NE;
        for (int e = 0; e < NE; e += 4) {
            float4 wv = *(const float4*)(wr + e);
            #pragma unroll
            for (int i = 0; i < 32; ++i) {
                float4 av = *(const float4*)&A[i][e];
                acc[i]=fmaf(av.x,wv.x,acc[i]); acc[i]=fmaf(av.y,wv.y,acc[i]);
                acc[i]=fmaf(av.z,wv.z,acc[i]); acc[i]=fmaf(av.w,wv.w,acc[i]);
            }
        }
    }
    float b1v = b1[tx];
    #pragma unroll
    for (int i = 0; i < 32; ++i) Bb[i][tx] = fmaxf(acc[i] + b1v, 0.f);
    __syncthreads();

    // ---- GEMM3 + residual + column sum over valid rows
    #pragma unroll
    for (int i = 0; i < 32; ++i) acc[i] = 0.f;
    {
        const float* wr = w2 + (size_t)tx * NE;
        for (int e = 0; e < NE; e += 4) {
            float4 wv = *(const float4*)(wr + e);
            #pragma unroll
            for (int i = 0; i < 32; ++i) {
                float4 av = *(const float4*)&Bb[i][e];
                acc[i]=fmaf(av.x,wv.x,acc[i]); acc[i]=fmaf(av.y,wv.y,acc[i]);
                acc[i]=fmaf(av.z,wv.z,acc[i]); acc[i]=fmaf(av.w,wv.w,acc[i]);
            }
        }
    }
    float b2v = b2[tx];
    float colsum = 0.f;
    #pragma unroll
    for (int i = 0; i < 32; ++i)
        colsum += (i < nr) ? (acc[i] + b2v + A[i][tx]) : 0.f;
    part[((size_t)bc * 8 + blockIdx.y) * NE + tx] = colsum;
}

// ---------------------------------------------------------------------------
// K4: finalize rep[b,c,:] = valid ? sum(part)/rv : 0
// ---------------------------------------------------------------------------
__global__ __launch_bounds__(256) void k_final(
    const float* __restrict__ part, const int* __restrict__ cols,
    const int* __restrict__ rows, float* __restrict__ out)
{
    int bc = blockIdx.x;
    int tx = threadIdx.x;
    int b = bc >> 5, c = bc & 31;
    float v = 0.f;
    if (c < cols[b]) {
        int rv = rows[b];
        int nt = (rv + 31) >> 5;
        float s = 0.f;
        for (int t2 = 0; t2 < nt; ++t2)
            s += part[((size_t)bc * 8 + t2) * NE + tx];
        v = s / (float)rv;
    }
    out[(size_t)bc * NE + tx] = v;
}

extern "C" void kernel_launch(void* const* d_in, const int* in_sizes, int n_in,
                              void* d_out, int out_size, void* d_ws, size_t ws_size,
                              hipStream_t stream)
{
    const float* x    = (const float*)d_in[0];
    const int*   cols = (const int*)d_in[1];
    const int*   rows = (const int*)d_in[2];
    const float* wqkv = (const float*)d_in[3];
    const float* bqkv = (const float*)d_in[4];
    const float* wout = (const float*)d_in[5];
    const float* bout = (const float*)d_in[6];
    const float* lng  = (const float*)d_in[7];
    const float* lnb  = (const float*)d_in[8];
    const float* w1   = (const float*)d_in[9];
    const float* b1   = (const float*)d_in[10];
    const float* w2   = (const float*)d_in[11];
    const float* b2   = (const float*)d_in[12];
    float* out = (float*)d_out;

    if (ws_size < WS_REQUIRED) return;   // graceful fail (poison absmax), not a fault

    unsigned short* qkv = (unsigned short*)d_ws;
    float* part = (float*)d_ws + PART_OFF_F;

    k_qkvproj<<<dim3(NB * NC, NR / 64, F3 / 64), 256, 0, stream>>>(x, wqkv, bqkv, cols, rows, qkv);
    k_attn   <<<dim3(NB * NC * NH), 256, 0, stream>>>(qkv, cols, rows);
    k_ffn    <<<dim3(NB * NC, NR / 32), 256, 0, stream>>>(qkv, wout, bout, lng, lnb,
                                                          w1, b1, w2, b2, cols, rows, part);
    k_final  <<<dim3(NB * NC), 256, 0, stream>>>(part, cols, rows, out);
}

// Round 5
// 835.974 us; speedup vs baseline: 3.7774x; 1.3578x over previous
//
#include <hip/hip_runtime.h>
#include <math.h>

#define NB 16
#define NC 32
#define NR 256
#define NE 256
#define NH 4
#define HDIM 64
#define F3 768

// ws layout (bytes):
//   qkv  bf16 [B][C][R][768]            0 .. 201,326,592   (ctx overwrites q-slot)
//   part f32  [B*C][4][256]             +2,097,152
//   wbf  bf16 [wout|w1|w2] 3x65536      +393,216
#define QKV_BYTES  201326592ULL
#define PART_BYTES 2097152ULL
#define WBF_BYTES  393216ULL
#define WS_REQUIRED (QKV_BYTES + PART_BYTES + WBF_BYTES)   // 203,816,960 B

typedef __attribute__((ext_vector_type(8))) short   short8v;   // MFMA A/B frag (8 bf16)
typedef __attribute__((ext_vector_type(4))) float   f32x4;     // MFMA C/D frag
typedef __attribute__((ext_vector_type(8))) unsigned short u16x8;

static __device__ __forceinline__ unsigned short f2bf(float f) {   // RNE f32->bf16
    unsigned u = __builtin_bit_cast(unsigned, f);
    u += 0x7FFFu + ((u >> 16) & 1u);
    return (unsigned short)(u >> 16);
}
static __device__ __forceinline__ float bf2f(unsigned short s) {
    unsigned u = ((unsigned)s) << 16;
    return __builtin_bit_cast(float, u);
}

// ---------------------------------------------------------------------------
// K0: f32 -> bf16 weight conversion (64 blocks x 256 thr x 4 elems = 65536)
// ---------------------------------------------------------------------------
__global__ __launch_bounds__(256) void k_wcvt(
    const float* __restrict__ src, unsigned short* __restrict__ dst)
{
    int i = (blockIdx.x * 256 + threadIdx.x) * 4;
    float4 v = *(const float4*)(src + i);
    ushort4 o = make_ushort4(f2bf(v.x), f2bf(v.y), f2bf(v.z), f2bf(v.w));
    *(ushort4*)(dst + i) = o;
}

// ---------------------------------------------------------------------------
// K1: QKV projection, bf16 MFMA (PASSED r4).  64x64 tile, BK=64, 4 waves.
// D: row=(l>>4)*4+j, col=l&15  [m89/m91 layout]
// ---------------------------------------------------------------------------
__global__ __launch_bounds__(256) void k_qkvproj(
    const float* __restrict__ x, const float* __restrict__ wqkv,
    const float* __restrict__ bqkv, const int* __restrict__ cols,
    const int* __restrict__ rows, unsigned short* __restrict__ qkv)
{
    int bc = blockIdx.x;
    int b = bc >> 5, c = bc & 31;
    if (c >= cols[b]) return;
    int rv = rows[b];
    int row0 = blockIdx.y * 64;
    if (row0 >= rv) return;
    int f0 = blockIdx.z * 64;

    __shared__ short As[64][72];   // +8 pad: 144B stride -> 2-way banks (free)
    __shared__ short Bs[64][72];

    int t = threadIdx.x;
    int wave = t >> 6, lane = t & 63;
    const float* xbc = x + (size_t)bc * (NR * NE);

    f32x4 acc[4];
    #pragma unroll
    for (int n = 0; n < 4; ++n) acc[n] = (f32x4){0.f, 0.f, 0.f, 0.f};

    for (int k0 = 0; k0 < NE; k0 += 64) {
        #pragma unroll
        for (int rr = 0; rr < 64; rr += 16) {
            int i = (t >> 4) + rr, kk = (t & 15) * 4;
            float4 v = *(const float4*)(xbc + (size_t)(row0 + i) * NE + k0 + kk);
            *(short4*)&As[i][kk] = make_short4((short)f2bf(v.x), (short)f2bf(v.y),
                                               (short)f2bf(v.z), (short)f2bf(v.w));
            float4 w = *(const float4*)(wqkv + (size_t)(f0 + i) * NE + k0 + kk);
            *(short4*)&Bs[i][kk] = make_short4((short)f2bf(w.x), (short)f2bf(w.y),
                                               (short)f2bf(w.z), (short)f2bf(w.w));
        }
        __syncthreads();
        #pragma unroll
        for (int kf = 0; kf < 2; ++kf) {
            short8v av = *(const short8v*)&As[16 * wave + (lane & 15)][kf * 32 + (lane >> 4) * 8];
            #pragma unroll
            for (int n = 0; n < 4; ++n) {
                short8v bv = *(const short8v*)&Bs[n * 16 + (lane & 15)][kf * 32 + (lane >> 4) * 8];
                acc[n] = __builtin_amdgcn_mfma_f32_16x16x32_bf16(av, bv, acc[n], 0, 0, 0);
            }
        }
        __syncthreads();
    }

    int rbase = row0 + 16 * wave + ((lane >> 4) << 2);
    #pragma unroll
    for (int n = 0; n < 4; ++n) {
        int f = f0 + n * 16 + (lane & 15);
        float bias = bqkv[f];
        float scl = (f < 256) ? 0.125f : 1.f;
        #pragma unroll
        for (int jj = 0; jj < 4; ++jj) {
            float val = (acc[n][jj] + bias) * scl;
            qkv[(size_t)((size_t)bc * NR + rbase + jj) * F3 + f] = f2bf(val);
        }
    }
}

// ---------------------------------------------------------------------------
// K2: flash attention per (b,c,h), fp32 core (unchanged from r4-passing).
// ---------------------------------------------------------------------------
__global__ __launch_bounds__(256) void k_attn(
    unsigned short* __restrict__ qkv, const int* __restrict__ cols,
    const int* __restrict__ rows)
{
    int blk = blockIdx.x;              // (b*32+c)*4 + h
    int h = blk & 3, bc = blk >> 2;
    int b = bc >> 5, c = bc & 31;
    if (c >= cols[b]) return;
    int rv = rows[b];
    int t = threadIdx.x;
    int nst = (rv + 63) >> 6;

    __shared__ float Kt[64][64];
    __shared__ float Vt[64][64];

    unsigned short* base = qkv + (size_t)bc * NR * F3;

    float q[HDIM];
    if (t < rv) {
        #pragma unroll
        for (int c8 = 0; c8 < 8; ++c8) {
            u16x8 uv = *(const u16x8*)(base + (size_t)t * F3 + h * HDIM + c8 * 8);
            #pragma unroll
            for (int j = 0; j < 8; ++j) q[c8 * 8 + j] = bf2f(uv[j]);
        }
    }

    float mrun = -INFINITY, l = 0.f;
    float cacc[HDIM];
    #pragma unroll
    for (int d = 0; d < HDIM; ++d) cacc[d] = 0.f;

    for (int st = 0; st < nst; ++st) {
        int s0 = st << 6;
        int ns = min(64, rv - s0);

        #pragma unroll
        for (int rep = 0; rep < 2; ++rep) {
            int slot = t + rep * 256;
            int s = slot >> 3, ch = slot & 7;
            const unsigned short* rp = base + (size_t)(s0 + s) * F3 + h * HDIM + ch * 8;
            u16x8 kv = *(const u16x8*)(rp + 256);
            u16x8 vv = *(const u16x8*)(rp + 512);
            float4 k0 = {bf2f(kv[0]), bf2f(kv[1]), bf2f(kv[2]), bf2f(kv[3])};
            float4 k1 = {bf2f(kv[4]), bf2f(kv[5]), bf2f(kv[6]), bf2f(kv[7])};
            float4 v0 = {bf2f(vv[0]), bf2f(vv[1]), bf2f(vv[2]), bf2f(vv[3])};
            float4 v1 = {bf2f(vv[4]), bf2f(vv[5]), bf2f(vv[6]), bf2f(vv[7])};
            *(float4*)&Kt[s][ch * 8]     = k0;
            *(float4*)&Kt[s][ch * 8 + 4] = k1;
            *(float4*)&Vt[s][ch * 8]     = v0;
            *(float4*)&Vt[s][ch * 8 + 4] = v1;
        }
        __syncthreads();

        if (t < rv) {
            for (int ss = 0; ss < ns; ss += 16) {
                float sc[16];
                float tmax = -INFINITY;
                #pragma unroll
                for (int u = 0; u < 16; ++u) {
                    float dot = 0.f;
                    #pragma unroll
                    for (int d = 0; d < HDIM; d += 4) {
                        float4 kv = *(const float4*)&Kt[ss + u][d];
                        dot = fmaf(q[d],   kv.x, dot); dot = fmaf(q[d+1], kv.y, dot);
                        dot = fmaf(q[d+2], kv.z, dot); dot = fmaf(q[d+3], kv.w, dot);
                    }
                    sc[u] = (ss + u < ns) ? dot : -INFINITY;
                    tmax = fmaxf(tmax, sc[u]);
                }
                float mnew = fmaxf(mrun, tmax);
                float r = __expf(mrun - mnew);
                l *= r;
                #pragma unroll
                for (int d = 0; d < HDIM; ++d) cacc[d] *= r;
                #pragma unroll
                for (int u = 0; u < 16; ++u) {
                    float p = __expf(sc[u] - mnew);
                    l += p;
                    #pragma unroll
                    for (int d = 0; d < HDIM; d += 4) {
                        float4 vv = *(const float4*)&Vt[ss + u][d];
                        cacc[d+0] = fmaf(p, vv.x, cacc[d+0]);
                        cacc[d+1] = fmaf(p, vv.y, cacc[d+1]);
                        cacc[d+2] = fmaf(p, vv.z, cacc[d+2]);
                        cacc[d+3] = fmaf(p, vv.w, cacc[d+3]);
                    }
                }
                mrun = mnew;
            }
        }
        __syncthreads();
    }

    if (t < rv) {
        float inv = 1.f / l;
        #pragma unroll
        for (int c8 = 0; c8 < 8; ++c8) {
            u16x8 o;
            #pragma unroll
            for (int j = 0; j < 8; ++j) o[j] = f2bf(cacc[c8 * 8 + j] * inv);
            *(u16x8*)(base + (size_t)t * F3 + h * HDIM + c8 * 8) = o;
        }
    }
}

// ---------------------------------------------------------------------------
// K3: MFMA out-proj + reg-LN + MFMA FFN + residual + colsum.
// One block per (bc, 64-row tile); wave w owns rows [16w,16w+16) x all 256 f.
// A-frags: ctx direct from global bf16; ln/h via bf16 LDS; B-frags from wbf.
// ---------------------------------------------------------------------------
__global__ __launch_bounds__(256) void k_ffn(
    const unsigned short* __restrict__ qkv, const unsigned short* __restrict__ wbf,
    const float* __restrict__ bout, const float* __restrict__ lng,
    const float* __restrict__ lnb, const float* __restrict__ b1,
    const float* __restrict__ b2, const int* __restrict__ cols,
    const int* __restrict__ rows, float* __restrict__ part)
{
    int bc = blockIdx.x;
    int b = bc >> 5, c = bc & 31;
    if (c >= cols[b]) return;
    int rv = rows[b];
    int row0 = blockIdx.y * 64;
    if (row0 >= rv) return;
    int nr = min(64, rv - row0);
    int t = threadIdx.x;
    int wave = t >> 6, lane = t & 63;
    int lr = lane & 15;                 // row-in-stripe / col-in-ntile
    int lk = lane >> 4;                 // k-subchunk / row-group (0..3)

    __shared__ __align__(16) unsigned short L1[64][264];  // ln bf16 (33.8 KB)
    __shared__ __align__(16) unsigned short L2[64][264];  // h  bf16 (33.8 KB)
    __shared__ float CS[4][256];                          // per-wave colsums

    const unsigned short* cbase = qkv + (size_t)((size_t)bc * NR + row0) * F3;
    const unsigned short* w_out = wbf;
    const unsigned short* w_1   = wbf + 65536;
    const unsigned short* w_2   = wbf + 131072;

    // ---- GEMM1: attn_out = ctx @ wout^T  (A from global ctx, B from wbf)
    short8v afr[8];
    #pragma unroll
    for (int kc = 0; kc < 8; ++kc)
        afr[kc] = *(const short8v*)(cbase + (size_t)(16 * wave + lr) * F3 + kc * 32 + lk * 8);

    f32x4 acc[16];
    #pragma unroll
    for (int n = 0; n < 16; ++n) acc[n] = (f32x4){0.f, 0.f, 0.f, 0.f};
    #pragma unroll
    for (int kc = 0; kc < 8; ++kc) {
        #pragma unroll
        for (int n = 0; n < 16; ++n) {
            short8v bfr = *(const short8v*)(w_out + (size_t)(n * 16 + lr) * NE + kc * 32 + lk * 8);
            acc[n] = __builtin_amdgcn_mfma_f32_16x16x32_bf16(afr[kc], bfr, acc[n], 0, 0, 0);
        }
    }

    // ---- + bout, LN stats in registers (row = 16w + lk*4 + j, 16 lanes/row)
    float sum_j[4] = {0,0,0,0}, sq_j[4] = {0,0,0,0};
    #pragma unroll
    for (int n = 0; n < 16; ++n) {
        float bo = bout[n * 16 + lr];
        #pragma unroll
        for (int j = 0; j < 4; ++j) {
            float v = acc[n][j] + bo;
            acc[n][j] = v;
            sum_j[j] += v;
            sq_j[j] = fmaf(v, v, sq_j[j]);
        }
    }
    float mu[4], rs[4];
    #pragma unroll
    for (int j = 0; j < 4; ++j) {
        float s = sum_j[j], q = sq_j[j];
        s += __shfl_xor(s, 1); q += __shfl_xor(q, 1);
        s += __shfl_xor(s, 2); q += __shfl_xor(q, 2);
        s += __shfl_xor(s, 4); q += __shfl_xor(q, 4);
        s += __shfl_xor(s, 8); q += __shfl_xor(q, 8);
        mu[j] = s * (1.f / 256.f);
        float var = q * (1.f / 256.f) - mu[j] * mu[j];
        rs[j] = rsqrtf(var + 1e-5f);
    }

    // ---- LN apply -> L1 (bf16)
    #pragma unroll
    for (int n = 0; n < 16; ++n) {
        int fcol = n * 16 + lr;
        float gg = lng[fcol], bb = lnb[fcol];
        #pragma unroll
        for (int j = 0; j < 4; ++j) {
            float v = fmaf((acc[n][j] - mu[j]) * rs[j], gg, bb);
            L1[16 * wave + lk * 4 + j][fcol] = f2bf(v);
        }
    }
    __syncthreads();

    // ---- GEMM2: h = relu(ln @ w1^T + b1) -> L2
    #pragma unroll
    for (int kc = 0; kc < 8; ++kc)
        afr[kc] = *(const short8v*)&L1[16 * wave + lr][kc * 32 + lk * 8];
    #pragma unroll
    for (int n = 0; n < 16; ++n) acc[n] = (f32x4){0.f, 0.f, 0.f, 0.f};
    #pragma unroll
    for (int kc = 0; kc < 8; ++kc) {
        #pragma unroll
        for (int n = 0; n < 16; ++n) {
            short8v bfr = *(const short8v*)(w_1 + (size_t)(n * 16 + lr) * NE + kc * 32 + lk * 8);
            acc[n] = __builtin_amdgcn_mfma_f32_16x16x32_bf16(afr[kc], bfr, acc[n], 0, 0, 0);
        }
    }
    #pragma unroll
    for (int n = 0; n < 16; ++n) {
        int fcol = n * 16 + lr;
        float bb = b1[fcol];
        #pragma unroll
        for (int j = 0; j < 4; ++j)
            L2[16 * wave + lk * 4 + j][fcol] = f2bf(fmaxf(acc[n][j] + bb, 0.f));
    }
    __syncthreads();

    // ---- GEMM3: ffn = h @ w2^T + b2; out = ln + ffn; colsum valid rows
    #pragma unroll
    for (int kc = 0; kc < 8; ++kc)
        afr[kc] = *(const short8v*)&L2[16 * wave + lr][kc * 32 + lk * 8];
    #pragma unroll
    for (int n = 0; n < 16; ++n) acc[n] = (f32x4){0.f, 0.f, 0.f, 0.f};
    #pragma unroll
    for (int kc = 0; kc < 8; ++kc) {
        #pragma unroll
        for (int n = 0; n < 16; ++n) {
            short8v bfr = *(const short8v*)(w_2 + (size_t)(n * 16 + lr) * NE + kc * 32 + lk * 8);
            acc[n] = __builtin_amdgcn_mfma_f32_16x16x32_bf16(afr[kc], bfr, acc[n], 0, 0, 0);
        }
    }
    float cs[16];
    #pragma unroll
    for (int n = 0; n < 16; ++n) {
        int fcol = n * 16 + lr;
        float bb = b2[fcol];
        float s = 0.f;
        #pragma unroll
        for (int j = 0; j < 4; ++j) {
            int rl = 16 * wave + lk * 4 + j;            // local row
            float v = acc[n][j] + bb + bf2f(L1[rl][fcol]);
            s += (rl < nr) ? v : 0.f;
        }
        s += __shfl_xor(s, 16);                         // combine 4 row-groups
        s += __shfl_xor(s, 32);
        cs[n] = s;                                      // full 16-row colsum
    }
    if (lane < 16) {
        #pragma unroll
        for (int n = 0; n < 16; ++n) CS[wave][n * 16 + lane] = cs[n];
    }
    __syncthreads();
    part[((size_t)bc * 4 + blockIdx.y) * NE + t] =
        CS[0][t] + CS[1][t] + CS[2][t] + CS[3][t];
}

// ---------------------------------------------------------------------------
// K4: finalize rep[b,c,:] = valid ? sum(part)/rv : 0
// ---------------------------------------------------------------------------
__global__ __launch_bounds__(256) void k_final(
    const float* __restrict__ part, const int* __restrict__ cols,
    const int* __restrict__ rows, float* __restrict__ out)
{
    int bc = blockIdx.x;
    int tx = threadIdx.x;
    int b = bc >> 5, c = bc & 31;
    float v = 0.f;
    if (c < cols[b]) {
        int rv = rows[b];
        int nt = (rv + 63) >> 6;
        float s = 0.f;
        for (int t2 = 0; t2 < nt; ++t2)
            s += part[((size_t)bc * 4 + t2) * NE + tx];
        v = s / (float)rv;
    }
    out[(size_t)bc * NE + tx] = v;
}

extern "C" void kernel_launch(void* const* d_in, const int* in_sizes, int n_in,
                              void* d_out, int out_size, void* d_ws, size_t ws_size,
                              hipStream_t stream)
{
    const float* x    = (const float*)d_in[0];
    const int*   cols = (const int*)d_in[1];
    const int*   rows = (const int*)d_in[2];
    const float* wqkv = (const float*)d_in[3];
    const float* bqkv = (const float*)d_in[4];
    const float* wout = (const float*)d_in[5];
    const float* bout = (const float*)d_in[6];
    const float* lng  = (const float*)d_in[7];
    const float* lnb  = (const float*)d_in[8];
    const float* w1   = (const float*)d_in[9];
    const float* b1   = (const float*)d_in[10];
    const float* w2   = (const float*)d_in[11];
    const float* b2   = (const float*)d_in[12];
    float* out = (float*)d_out;

    if (ws_size < WS_REQUIRED) return;   // graceful fail, not a fault

    unsigned short* qkv  = (unsigned short*)d_ws;
    float*          part = (float*)((char*)d_ws + QKV_BYTES);
    unsigned short* wbf  = (unsigned short*)((char*)d_ws + QKV_BYTES + PART_BYTES);

    k_wcvt<<<dim3(64), 256, 0, stream>>>(wout, wbf);
    k_wcvt<<<dim3(64), 256, 0, stream>>>(w1,   wbf + 65536);
    k_wcvt<<<dim3(64), 256, 0, stream>>>(w2,   wbf + 131072);
    k_qkvproj<<<dim3(NB * NC, NR / 64, F3 / 64), 256, 0, stream>>>(x, wqkv, bqkv, cols, rows, qkv);
    k_attn   <<<dim3(NB * NC * NH), 256, 0, stream>>>(qkv, cols, rows);
    k_ffn    <<<dim3(NB * NC, NR / 64), 256, 0, stream>>>(qkv, wbf, bout, lng, lnb,
                                                          b1, b2, cols, rows, part);
    k_final  <<<dim3(NB * NC), 256, 0, stream>>>(part, cols, rows, out);
}